// Round 6
// baseline (392.681 us; speedup 1.0000x reference)
//
#include <hip/hip_runtime.h>
#include <hip/hip_fp16.h>

namespace {

constexpr int kB = 128, kI = 1152, kD = 8, kN = 32, kE = 16;
constexpr int kTI = 2;                  // input capsules per sub-chunk (W regs = 64 half2)
constexpr int kCH = 4;                  // sub-chunks per block
constexpr int kIB = kTI * kCH;          // 8 input capsules per block
constexpr int kNG = kI / kIB;           // 144 i-groups
constexpr int kCG = 6;                  // chunk groups for 2-level reduce
constexpr int kGPG = kNG / kCG;         // 24 groups per reduce group

constexpr size_t kPartBytes  = (size_t)kNG * kB * kN * kE * 2;   // 18.9 MB fp16
constexpr size_t kPart2Bytes = (size_t)kCG * kB * kN * kE * 4;   // 1.5 MB f32
constexpr size_t kVsumBytes  = (size_t)kB * kN * kE * 4;         // 256 KB f32

typedef _Float16 h2v __attribute__((ext_vector_type(2)));

__device__ __forceinline__ float fdot2(__half2 a, __half2 b, float c) {
#if defined(__has_builtin) && __has_builtin(__builtin_amdgcn_fdot2)
  return __builtin_amdgcn_fdot2(__builtin_bit_cast(h2v, a),
                                __builtin_bit_cast(h2v, b), c, false);
#else
  float2 af = __half22float2(a), bf = __half22float2(b);
  return fmaf(af.y, bf.y, fmaf(af.x, bf.x, c));
#endif
}

__device__ __forceinline__ float frcp(float v) {
#if defined(__has_builtin) && __has_builtin(__builtin_amdgcn_rcpf)
  return __builtin_amdgcn_rcpf(v);
#else
  return 1.0f / v;
#endif
}

union I4H { int4 v; __half2 h[4]; };

// Opaque register barrier: result of asm cannot be rematerialized -> the
// loaded W values MUST stay resident in VGPRs.
__device__ __forceinline__ void keep(int4& v) {
  asm volatile("" : "+v"(v.x), "+v"(v.y), "+v"(v.z), "+v"(v.w));
}

// uh[k] (4 half2 = 8 e for this lane's e-octet) = sum_d x_d * W[d][e...]
__device__ __forceinline__ void uh_comp(const __half2* __restrict__ xp,
                                        const I4H* __restrict__ wrow,
                                        __half2 uh[4]) {
  I4H xa, xb;
  xa.v = reinterpret_cast<const int4*>(xp)[0];   // dup x_d, d=0..3 (LDS broadcast)
  xb.v = reinterpret_cast<const int4*>(xp)[1];   // d=4..7
#pragma unroll
  for (int k = 0; k < 4; ++k) uh[k] = __hmul2(xa.h[0], wrow[0].h[k]);
#pragma unroll
  for (int d = 1; d < 4; ++d)
#pragma unroll
    for (int k = 0; k < 4; ++k) uh[k] = __hfma2(xa.h[d], wrow[d].h[k], uh[k]);
#pragma unroll
  for (int d = 0; d < 4; ++d)
#pragma unroll
    for (int k = 0; k < 4; ++k) uh[k] = __hfma2(xb.h[d], wrow[4 + d].h[k], uh[k]);
}

// Routing pass. Lanes = (eh, n). Block: 8 i (4 sub-chunks of 2), 16 batches
// (4 per wave). Per sub-chunk: stage W coalesced->swizzled LDS -> b128 ->
// VGPRs (laundered), phase A: all logits, phase B: 8 interleaved softmax
// chains, phase C: s accumulation (uh recomputed). s held in regs across subs.
template<int PASS>
__global__ __launch_bounds__(256, 3)
void caps_pass(const float* __restrict__ x, const float* __restrict__ W,
               const float* __restrict__ bias, const __half* __restrict__ vsh,
               __half* __restrict__ part)
{
  __shared__ int4    wlds[kTI * kD * 64];     // 16 KB swizzled W sub-slice
  __shared__ __half2 xlds[16][kIB * kD];      // 4 KB dup-half2 x tile
  __shared__ float   blds[kIB * kN];          // 1 KB bias tile

  const int g  = (int)blockIdx.x;
  const int g0 = g * kIB;
  const int b0 = (int)blockIdx.y * 16;
  const int t  = (int)threadIdx.x;
  const int L  = t & 63;
  const int wv = t >> 6;
  const int eh = L >> 5;
  const int n  = L & 31;

  // ---- stage x tile (1024 f32) + bias tile (256 f32), once ----
  {
    const int br = t >> 4, q = t & 15;
    const float4 f4 = *reinterpret_cast<const float4*>(
        x + (size_t)(b0 + br) * (kI * kD) + (size_t)g0 * kD + q * 4);
    xlds[br][q * 4 + 0] = __half2half2(__float2half_rn(f4.x));
    xlds[br][q * 4 + 1] = __half2half2(__float2half_rn(f4.y));
    xlds[br][q * 4 + 2] = __half2half2(__float2half_rn(f4.z));
    xlds[br][q * 4 + 3] = __half2half2(__float2half_rn(f4.w));
    blds[t] = bias[(size_t)g0 * kN + t];
  }

  __half2 sAcc[4][4];                 // [bb][k] persists across sub-chunks
#pragma unroll
  for (int bb = 0; bb < 4; ++bb)
#pragma unroll
    for (int k = 0; k < 4; ++k) sAcc[bb][k] = __half2half2(__float2half(0.f));

#pragma unroll 1
  for (int s = 0; s < kCH; ++s) {
    __syncthreads();   // prev sub's reads done (also covers x/bias staging)
    // ---- W sub-slice (8192 f32) coalesced -> swizzled fp16 LDS ----
    {
      const float* wsrc = W + (size_t)(g0 + s * kTI) * (kN * kD * kE);
#pragma unroll
      for (int j = 0; j < 8; ++j) {
        const int f = (j * 256 + t) * 4;            // f32 index in slice
        const float4 w4 = *reinterpret_cast<const float4*>(wsrc + f);
        const int il = f >> 12, rem = f & 4095;
        const int nn = rem >> 7, dd = (rem >> 4) & 7, e = rem & 15;
        const int r = il * 8 + dd;
        const int col = (((e >> 3) << 5) + nn) ^ (r & 7);
        __half2* wh = reinterpret_cast<__half2*>(&wlds[r * 64 + col]);
        const int pp = (e & 7) >> 1;
        wh[pp]     = __floats2half2_rn(w4.x, w4.y);
        wh[pp + 1] = __floats2half2_rn(w4.z, w4.w);
      }
    }
    __syncthreads();
    // ---- W -> VGPRs (conflict-free b128), laundered so it stays resident ----
    I4H wreg[kTI][kD];
#pragma unroll
    for (int i = 0; i < kTI; ++i)
#pragma unroll
      for (int d = 0; d < kD; ++d) {
        const int r = i * 8 + d;
        wreg[i][d].v = wlds[r * 64 + (L ^ (r & 7))];
        keep(wreg[i][d].v);
      }

    if (PASS == 0) {
      // c depends only on (i, n): softmax of bias row, shared by all b
      __half2 c0[kTI];
#pragma unroll
      for (int i = 0; i < kTI; ++i) {
        const float lg = blds[(s * kTI + i) * kN + n];
        float m = lg;
#pragma unroll
        for (int o = 1; o <= 16; o <<= 1) m = fmaxf(m, __shfl_xor(m, o, 64));
        const float ev = __expf(lg - m);
        float sm = ev;
#pragma unroll
        for (int o = 1; o <= 16; o <<= 1) sm += __shfl_xor(sm, o, 64);
        c0[i] = __half2half2(__float2half_rn(ev * frcp(sm)));
      }
#pragma unroll
      for (int bb = 0; bb < 4; ++bb) {
        const int bl = wv * 4 + bb;
#pragma unroll
        for (int i = 0; i < kTI; ++i) {
          __half2 uh[4];
          uh_comp(&xlds[bl][(s * kTI + i) * kD], wreg[i], uh);
#pragma unroll
          for (int k = 0; k < 4; ++k) sAcc[bb][k] = __hfma2(c0[i], uh[k], sAcc[bb][k]);
        }
      }
    } else {
      // ---- phase A: all 8 logits (bb x i) ----
      float lgv[4][kTI];
#pragma unroll
      for (int bb = 0; bb < 4; ++bb) {
        const int bl = wv * 4 + bb;
        I4H vq;
        vq.v = *reinterpret_cast<const int4*>(
            vsh + ((size_t)(b0 + bl) * kN + n) * kE + eh * 8);
#pragma unroll
        for (int i = 0; i < kTI; ++i) {
          __half2 uh[4];
          uh_comp(&xlds[bl][(s * kTI + i) * kD], wreg[i], uh);
          float lg = blds[(s * kTI + i) * kN + n];
#pragma unroll
          for (int k = 0; k < 4; ++k) lg = fdot2(uh[k], vq.h[k], lg);
          lg += __shfl_xor(lg, 32, 64);          // add both e-octets
          lgv[bb][i] = lg;
        }
      }
      // ---- phase B: 8 independent softmax chains, interleaved ----
      __half2 cc[4][kTI];
#pragma unroll
      for (int bb = 0; bb < 4; ++bb)
#pragma unroll
        for (int i = 0; i < kTI; ++i) {
          float m = lgv[bb][i];
#pragma unroll
          for (int o = 1; o <= 16; o <<= 1) m = fmaxf(m, __shfl_xor(m, o, 64));
          const float ev = __expf(lgv[bb][i] - m);
          float sm = ev;
#pragma unroll
          for (int o = 1; o <= 16; o <<= 1) sm += __shfl_xor(sm, o, 64);
          cc[bb][i] = __half2half2(__float2half_rn(ev * frcp(sm)));
        }
      // ---- phase C: s accumulation (uh recomputed) ----
#pragma unroll
      for (int bb = 0; bb < 4; ++bb) {
        const int bl = wv * 4 + bb;
#pragma unroll
        for (int i = 0; i < kTI; ++i) {
          __half2 uh[4];
          uh_comp(&xlds[bl][(s * kTI + i) * kD], wreg[i], uh);
#pragma unroll
          for (int k = 0; k < 4; ++k) sAcc[bb][k] = __hfma2(cc[bb][i], uh[k], sAcc[bb][k]);
        }
      }
    }
  }

  // ---- store partials: part[g][b][n][e], 1 KB contiguous per wave-inst ----
#pragma unroll
  for (int bb = 0; bb < 4; ++bb) {
    const int b = b0 + wv * 4 + bb;
    I4H o;
#pragma unroll
    for (int k = 0; k < 4; ++k) o.h[k] = sAcc[bb][k];
    *reinterpret_cast<int4*>(
        part + (((size_t)g * kB + b) * kN + n) * kE + eh * 8) = o.v;
  }
}

// Level-1 reduce: sum 24 i-groups of fp16 partials -> f32 partial2[cg][b][n][e]
__global__ __launch_bounds__(256)
void caps_reduce1(const __half* __restrict__ part, float* __restrict__ partial2)
{
  const int cg = (int)blockIdx.y;
  const int t = (int)threadIdx.x;
  const int b = (int)blockIdx.x * 4 + (t >> 6);
  const int l = t & 63;
  const __half* p0 = part + ((size_t)(cg * kGPG) * kB + b) * (kN * kE) + l * 8;
  constexpr size_t gStride = (size_t)kB * kN * kE;
  float acc[8] = {0.f, 0.f, 0.f, 0.f, 0.f, 0.f, 0.f, 0.f};
#pragma unroll 4
  for (int ch = 0; ch < kGPG; ++ch) {
    I4H q; q.v = *reinterpret_cast<const int4*>(p0 + (size_t)ch * gStride);
#pragma unroll
    for (int k = 0; k < 4; ++k) {
      float2 f = __half22float2(q.h[k]);
      acc[2 * k] += f.x; acc[2 * k + 1] += f.y;
    }
  }
  float* dst = partial2 + ((size_t)cg * kB + b) * (kN * kE) + l * 8;
  *reinterpret_cast<float4*>(dst)     = make_float4(acc[0], acc[1], acc[2], acc[3]);
  *reinterpret_cast<float4*>(dst + 4) = make_float4(acc[4], acc[5], acc[6], acc[7]);
}

// Final: sum 6 chunk-groups, squash. MODE 0: vsum=v,vsh=v; 1: vsum+=v; 2: out=v.
template<int MODE>
__global__ __launch_bounds__(256)
void caps_final(const float* __restrict__ partial2, float* __restrict__ vsum,
                __half* __restrict__ vsh, float* __restrict__ out)
{
  const int b = (int)blockIdx.x;
  const int t = (int)threadIdx.x;
  const int nl = t >> 3, ep = t & 7;
  const size_t o = ((size_t)b * kN + nl) * kE + ep * 2;
  float ax = 0.f, ay = 0.f;
#pragma unroll
  for (int cg = 0; cg < kCG; ++cg) {
    float2 f = *reinterpret_cast<const float2*>(
        partial2 + (size_t)cg * kB * kN * kE + o);
    ax += f.x; ay += f.y;
  }
  float s2 = ax * ax + ay * ay;
  s2 += __shfl_xor(s2, 1, 64);
  s2 += __shfl_xor(s2, 2, 64);
  s2 += __shfl_xor(s2, 4, 64);
  const float sc = (s2 / (1.f + s2)) * rsqrtf(fmaxf(s2, 1e-30f));
  float vx = ax * sc, vy = ay * sc;
  if (MODE == 2) {
    *reinterpret_cast<float2*>(out + o) = make_float2(vx, vy);
  } else {
    if (MODE == 1) {
      float2 old = *reinterpret_cast<const float2*>(vsum + o);
      vx += old.x; vy += old.y;
    }
    *reinterpret_cast<float2*>(vsum + o) = make_float2(vx, vy);
    *reinterpret_cast<__half2*>(vsh + o) = __floats2half2_rn(vx, vy);
  }
}

}  // namespace

extern "C" void kernel_launch(void* const* d_in, const int* in_sizes, int n_in,
                              void* d_out, int out_size, void* d_ws, size_t ws_size,
                              hipStream_t stream) {
  (void)in_sizes; (void)n_in; (void)out_size; (void)ws_size;
  const float* x    = reinterpret_cast<const float*>(d_in[0]);
  const float* W    = reinterpret_cast<const float*>(d_in[1]);
  const float* bias = reinterpret_cast<const float*>(d_in[2]);
  float* out = reinterpret_cast<float*>(d_out);

  char* ws = reinterpret_cast<char*>(d_ws);
  __half* part     = reinterpret_cast<__half*>(ws);
  float*  partial2 = reinterpret_cast<float*>(ws + kPartBytes);
  float*  vsum     = reinterpret_cast<float*>(ws + kPartBytes + kPart2Bytes);
  __half* vsh      = reinterpret_cast<__half*>(ws + kPartBytes + kPart2Bytes + kVsumBytes);

  dim3 pg(kNG, kB / 16), pb(256);
  dim3 rg(kB / 4, kCG), rb(256);

  // iter 0: c = softmax(bias); v0 -> vsum/vsh
  caps_pass<0><<<pg, pb, 0, stream>>>(x, W, bias, vsh, part);
  caps_reduce1<<<rg, rb, 0, stream>>>(part, partial2);
  caps_final<0><<<kB, 256, 0, stream>>>(partial2, vsum, vsh, out);
  // iter 1: logits = bias + <u_hat, v0>; vsum += v1
  caps_pass<1><<<pg, pb, 0, stream>>>(x, W, bias, vsh, part);
  caps_reduce1<<<rg, rb, 0, stream>>>(part, partial2);
  caps_final<1><<<kB, 256, 0, stream>>>(partial2, vsum, vsh, out);
  // iter 2: logits = bias + <u_hat, v0+v1>; out = squash(s)
  caps_pass<2><<<pg, pb, 0, stream>>>(x, W, bias, vsh, part);
  caps_reduce1<<<rg, rb, 0, stream>>>(part, partial2);
  caps_final<2><<<kB, 256, 0, stream>>>(partial2, vsum, vsh, out);
}

// Round 7
// 223.967 us; speedup vs baseline: 1.7533x; 1.7533x over previous
//
#include <hip/hip_runtime.h>
#include <hip/hip_fp16.h>

namespace {

constexpr int kB = 128, kI = 1152, kD = 8, kN = 32, kE = 16;
constexpr int kTI = 4;                 // input capsules per chunk (W = 128 VGPR)
constexpr int kNC = kI / kTI;          // 288 chunks
constexpr int kCG = 4;                 // chunk groups for 2-level reduce
constexpr int kCPG = kNC / kCG;        // 72 chunks per group

constexpr size_t kPartBytes  = (size_t)kNC * kB * kN * kE * 2;   // 36.9 MB fp16
constexpr size_t kPart2Bytes = (size_t)kCG * kB * kN * kE * 4;   // 1 MB f32
constexpr size_t kVsumBytes  = (size_t)kB * kN * kE * 4;         // 256 KB f32

typedef _Float16 h2v __attribute__((ext_vector_type(2)));

__device__ __forceinline__ float fdot2(__half2 a, __half2 b, float c) {
#if defined(__has_builtin) && __has_builtin(__builtin_amdgcn_fdot2)
  return __builtin_amdgcn_fdot2(__builtin_bit_cast(h2v, a),
                                __builtin_bit_cast(h2v, b), c, false);
#else
  float2 af = __half22float2(a), bf = __half22float2(b);
  return fmaf(af.y, bf.y, fmaf(af.x, bf.x, c));
#endif
}

__device__ __forceinline__ float frcp(float v) {
#if defined(__has_builtin) && __has_builtin(__builtin_amdgcn_rcpf)
  return __builtin_amdgcn_rcpf(v);
#else
  return 1.0f / v;
#endif
}

union I4H { int4 v; __half2 h[4]; };

// Opaque register barrier: an asm result cannot be rematerialized, so the
// loaded W values MUST stay resident in VGPRs (round-3 failure mode fix).
__device__ __forceinline__ void keep(int4& v) {
  asm volatile("" : "+v"(v.x), "+v"(v.y), "+v"(v.z), "+v"(v.w));
}

// uh[k] (4 half2 = 8 e for this lane's e-octet) = sum_d x_d * W[d][e..]
__device__ __forceinline__ void uh_comp(const __half2* __restrict__ xp,
                                        const I4H* __restrict__ wrow,
                                        __half2 uh[4]) {
  I4H xa, xb;
  xa.v = reinterpret_cast<const int4*>(xp)[0];   // dup x_d, d=0..3 (LDS broadcast)
  xb.v = reinterpret_cast<const int4*>(xp)[1];   // d=4..7
#pragma unroll
  for (int k = 0; k < 4; ++k) uh[k] = __hmul2(xa.h[0], wrow[0].h[k]);
#pragma unroll
  for (int d = 1; d < 4; ++d)
#pragma unroll
    for (int k = 0; k < 4; ++k) uh[k] = __hfma2(xa.h[d], wrow[d].h[k], uh[k]);
#pragma unroll
  for (int d = 0; d < 4; ++d)
#pragma unroll
    for (int k = 0; k < 4; ++k) uh[k] = __hfma2(xb.h[d], wrow[4 + d].h[k], uh[k]);
}

// Routing pass. Lanes = (eh, n). Block = 4 waves, 32 batches (8/wave), one
// 4-i chunk. W staged coalesced -> XOR-swizzled LDS -> b128 -> VGPRs
// (laundered, resident). Per bb: phase A (4x uh+logit), phase B (4
// interleaved softmax chains), phase C (4x s += c*uh, no memory reads).
template<int PASS>
__global__ __launch_bounds__(256, 2)
void caps_pass(const float* __restrict__ x, const float* __restrict__ W,
               const float* __restrict__ bias, const __half* __restrict__ vsh,
               __half* __restrict__ part)
{
  __shared__ int4    wlds[kTI * kD * 64];   // 32 KB swizzled W chunk
  __shared__ __half2 xlds[32][kTI * kD];    // 4 KB dup-half2 x tile

  const int chunk = (int)blockIdx.x;
  const int i0 = chunk * kTI;
  const int b0 = (int)blockIdx.y * 32;
  const int t  = (int)threadIdx.x;
  const int L  = t & 63;
  const int wv = t >> 6;
  const int eh = L >> 5;
  const int n  = L & 31;

  // ---- stage x tile: 32 b x (4 i x 8 d) dup-half2 ----
  {
    const int r = t >> 3, c = (t & 7) * 4;
    const float4 f4 = *reinterpret_cast<const float4*>(
        x + (size_t)(b0 + r) * (kI * kD) + (size_t)i0 * kD + c);
    xlds[r][c + 0] = __half2half2(__float2half_rn(f4.x));
    xlds[r][c + 1] = __half2half2(__float2half_rn(f4.y));
    xlds[r][c + 2] = __half2half2(__float2half_rn(f4.z));
    xlds[r][c + 3] = __half2half2(__float2half_rn(f4.w));
  }
  // ---- stage W chunk (16384 f32) coalesced -> swizzled fp16 LDS ----
  {
    const float* wsrc = W + (size_t)i0 * (kN * kD * kE);
#pragma unroll
    for (int j = 0; j < 16; ++j) {
      const int f = (j * 256 + t) * 4;             // f32 index in 64 KB slice
      const float4 w4 = *reinterpret_cast<const float4*>(wsrc + f);
      const int il = f >> 12, rem = f & 4095;
      const int nn = rem >> 7, dd = (rem >> 4) & 7, e = rem & 15;
      const int r = il * 8 + dd;
      const int col = (((e >> 3) << 5) + nn) ^ (r & 7);
      __half2* wh = reinterpret_cast<__half2*>(&wlds[r * 64 + col]);
      const int pp = (e & 7) >> 1;                 // 0 or 2
      wh[pp]     = __floats2half2_rn(w4.x, w4.y);
      wh[pp + 1] = __floats2half2_rn(w4.z, w4.w);
    }
  }
  __syncthreads();

  // ---- W -> VGPRs (contiguous b128, conflict-free), laundered ----
  I4H wreg[kTI][kD];
#pragma unroll
  for (int i = 0; i < kTI; ++i)
#pragma unroll
    for (int d = 0; d < kD; ++d) {
      const int r = i * 8 + d;
      wreg[i][d].v = wlds[r * 64 + (L ^ (r & 7))];
      keep(wreg[i][d].v);
    }

  float bf[kTI];
#pragma unroll
  for (int i = 0; i < kTI; ++i) bf[i] = bias[(size_t)(i0 + i) * kN + n];

  // PASS 0: c depends only on (i, n) -> softmax once, outside the bb-loop
  __half2 c0[kTI];
  if (PASS == 0) {
#pragma unroll
    for (int i = 0; i < kTI; ++i) {
      float m = bf[i];
#pragma unroll
      for (int o = 1; o <= 16; o <<= 1) m = fmaxf(m, __shfl_xor(m, o, 64));
      const float ev = __expf(bf[i] - m);
      float sm = ev;
#pragma unroll
      for (int o = 1; o <= 16; o <<= 1) sm += __shfl_xor(sm, o, 64);
      c0[i] = __half2half2(__float2half_rn(ev * frcp(sm)));
    }
  }

#pragma unroll 1
  for (int bb = 0; bb < 8; ++bb) {
    const int bl = wv * 8 + bb;
    const int b = b0 + bl;

    __half2 s[4];
#pragma unroll
    for (int k = 0; k < 4; ++k) s[k] = __half2half2(__float2half(0.f));

    if (PASS == 0) {
#pragma unroll
      for (int i = 0; i < kTI; ++i) {
        __half2 uh[4];
        uh_comp(&xlds[bl][i * kD], wreg[i], uh);
#pragma unroll
        for (int k = 0; k < 4; ++k) s[k] = __hfma2(c0[i], uh[k], s[k]);
      }
    } else {
      I4H vq;
      vq.v = *reinterpret_cast<const int4*>(
          vsh + ((size_t)b * kN + n) * kE + eh * 8);
      // phase A: uh + logits for all 4 i (uh kept in regs)
      __half2 uhs[kTI][4];
      float lgv[kTI];
#pragma unroll
      for (int i = 0; i < kTI; ++i) {
        uh_comp(&xlds[bl][i * kD], wreg[i], uhs[i]);
        float lg = bf[i];
#pragma unroll
        for (int k = 0; k < 4; ++k) lg = fdot2(uhs[i][k], vq.h[k], lg);
        lg += __shfl_xor(lg, 32, 64);    // add both e-octets
        lgv[i] = lg;
      }
      // phase B: 4 independent softmax chains (interleaved by ILP)
      __half2 cc[kTI];
#pragma unroll
      for (int i = 0; i < kTI; ++i) {
        float m = lgv[i];
#pragma unroll
        for (int o = 1; o <= 16; o <<= 1) m = fmaxf(m, __shfl_xor(m, o, 64));
        const float ev = __expf(lgv[i] - m);
        float sm = ev;
#pragma unroll
        for (int o = 1; o <= 16; o <<= 1) sm += __shfl_xor(sm, o, 64);
        cc[i] = __half2half2(__float2half_rn(ev * frcp(sm)));
      }
      // phase C: accumulate (register-only)
#pragma unroll
      for (int i = 0; i < kTI; ++i)
#pragma unroll
        for (int k = 0; k < 4; ++k) s[k] = __hfma2(cc[i], uhs[i][k], s[k]);
    }

    I4H o;
#pragma unroll
    for (int k = 0; k < 4; ++k) o.h[k] = s[k];
    // part[ch][b][n][e]: 1 KB contiguous per wave-store
    *reinterpret_cast<int4*>(
        part + (((size_t)chunk * kB + b) * kN + n) * kE + eh * 8) = o.v;
  }
}

// Level-1 reduce: sum 72 chunks of fp16 partials -> f32 partial2[cg][b][n][e].
__global__ __launch_bounds__(256)
void caps_reduce1(const __half* __restrict__ part, float* __restrict__ partial2)
{
  const int cg = (int)blockIdx.y;
  const int t = (int)threadIdx.x;
  const int b = (int)blockIdx.x * 4 + (t >> 6);
  const int l = t & 63;                      // int4 slot: halves l*8 .. l*8+7
  const __half* p0 = part + ((size_t)(cg * kCPG) * kB + b) * (kN * kE) + l * 8;
  constexpr size_t chStride = (size_t)kB * kN * kE;   // halves per chunk
  float acc[8] = {0.f, 0.f, 0.f, 0.f, 0.f, 0.f, 0.f, 0.f};
#pragma unroll 4
  for (int ch = 0; ch < kCPG; ++ch) {
    I4H q; q.v = *reinterpret_cast<const int4*>(p0 + (size_t)ch * chStride);
#pragma unroll
    for (int k = 0; k < 4; ++k) {
      float2 f = __half22float2(q.h[k]);
      acc[2 * k] += f.x; acc[2 * k + 1] += f.y;
    }
  }
  float* dst = partial2 + ((size_t)cg * kB + b) * (kN * kE) + l * 8;
  *reinterpret_cast<float4*>(dst)     = make_float4(acc[0], acc[1], acc[2], acc[3]);
  *reinterpret_cast<float4*>(dst + 4) = make_float4(acc[4], acc[5], acc[6], acc[7]);
}

// Final: sum 4 chunk-groups, squash. MODE 0: vsum=v,vsh=v; 1: vsum+=v; 2: out=v.
template<int MODE>
__global__ __launch_bounds__(256)
void caps_final(const float* __restrict__ partial2, float* __restrict__ vsum,
                __half* __restrict__ vsh, float* __restrict__ out)
{
  const int b = (int)blockIdx.x;
  const int t = (int)threadIdx.x;
  const int nl = t >> 3, ep = t & 7;
  const size_t o = ((size_t)b * kN + nl) * kE + ep * 2;
  float ax = 0.f, ay = 0.f;
#pragma unroll
  for (int cg = 0; cg < kCG; ++cg) {
    float2 f = *reinterpret_cast<const float2*>(
        partial2 + (size_t)cg * kB * kN * kE + o);
    ax += f.x; ay += f.y;
  }
  float s2 = ax * ax + ay * ay;
  s2 += __shfl_xor(s2, 1, 64);
  s2 += __shfl_xor(s2, 2, 64);
  s2 += __shfl_xor(s2, 4, 64);
  const float sc = (s2 / (1.f + s2)) * rsqrtf(fmaxf(s2, 1e-30f));
  float vx = ax * sc, vy = ay * sc;
  if (MODE == 2) {
    *reinterpret_cast<float2*>(out + o) = make_float2(vx, vy);
  } else {
    if (MODE == 1) {
      float2 old = *reinterpret_cast<const float2*>(vsum + o);
      vx += old.x; vy += old.y;
    }
    *reinterpret_cast<float2*>(vsum + o) = make_float2(vx, vy);
    *reinterpret_cast<__half2*>(vsh + o) = __floats2half2_rn(vx, vy);
  }
}

}  // namespace

extern "C" void kernel_launch(void* const* d_in, const int* in_sizes, int n_in,
                              void* d_out, int out_size, void* d_ws, size_t ws_size,
                              hipStream_t stream) {
  (void)in_sizes; (void)n_in; (void)out_size; (void)ws_size;
  const float* x    = reinterpret_cast<const float*>(d_in[0]);
  const float* W    = reinterpret_cast<const float*>(d_in[1]);
  const float* bias = reinterpret_cast<const float*>(d_in[2]);
  float* out = reinterpret_cast<float*>(d_out);

  char* ws = reinterpret_cast<char*>(d_ws);
  __half* part     = reinterpret_cast<__half*>(ws);
  float*  partial2 = reinterpret_cast<float*>(ws + kPartBytes);
  float*  vsum     = reinterpret_cast<float*>(ws + kPartBytes + kPart2Bytes);
  __half* vsh      = reinterpret_cast<__half*>(ws + kPartBytes + kPart2Bytes + kVsumBytes);

  dim3 pg(kNC, kB / 32), pb(256);
  dim3 rg(kB / 4, kCG), rb(256);

  // iter 0: c = softmax(bias); v0 -> vsum/vsh
  caps_pass<0><<<pg, pb, 0, stream>>>(x, W, bias, vsh, part);
  caps_reduce1<<<rg, rb, 0, stream>>>(part, partial2);
  caps_final<0><<<kB, 256, 0, stream>>>(partial2, vsum, vsh, out);
  // iter 1: logits = bias + <u_hat, v0>; vsum += v1
  caps_pass<1><<<pg, pb, 0, stream>>>(x, W, bias, vsh, part);
  caps_reduce1<<<rg, rb, 0, stream>>>(part, partial2);
  caps_final<1><<<kB, 256, 0, stream>>>(partial2, vsum, vsh, out);
  // iter 2: logits = bias + <u_hat, v0+v1>; out = squash(s)
  caps_pass<2><<<pg, pb, 0, stream>>>(x, W, bias, vsh, part);
  caps_reduce1<<<rg, rb, 0, stream>>>(part, partial2);
  caps_final<2><<<kB, 256, 0, stream>>>(partial2, vsum, vsh, out);
}